// Round 1
// baseline (469.642 us; speedup 1.0000x reference)
//
#include <hip/hip_runtime.h>
#include <hip/hip_bf16.h>

// Problem constants (B,N,HC,HH,K,D) = (64,300,64,64,3,10)
#define BB 64
#define NN 300
#define HH 64
#define RTOT (BB*NN)          // 19200 rows
#define KIO  (3*HH*HH)        // 12288: weights_pool inner size per d
#define JOUT (HH*HH)          // 4096 output cols

typedef __attribute__((ext_vector_type(8))) _Float16 f16x8;
typedef __attribute__((ext_vector_type(4))) float floatx4;

__device__ inline float tanh_fast(float x) {
    float e = __expf(2.f * x);
    return 1.f - 2.f * __builtin_amdgcn_rcpf(e + 1.f);
}

// A[n,m] = softmax_m( relu(E[n]·E[m]) ), one block per row n
__global__ __launch_bounds__(256) void k_adjacency(const float* __restrict__ E,
                                                   float* __restrict__ A) {
    __shared__ float sE[16];
    __shared__ float row[NN];
    __shared__ float red[256];
    int n = blockIdx.x, tid = threadIdx.x;
    if (tid < 10) sE[tid] = E[n*10 + tid];
    __syncthreads();
    float lmax = -1e30f;
    for (int m = tid; m < NN; m += 256) {
        float s = 0.f;
        #pragma unroll
        for (int d = 0; d < 10; ++d) s += sE[d] * E[m*10 + d];
        s = fmaxf(s, 0.f);
        row[m] = s;
        lmax = fmaxf(lmax, s);
    }
    red[tid] = lmax; __syncthreads();
    for (int off = 128; off > 0; off >>= 1) {
        if (tid < off) red[tid] = fmaxf(red[tid], red[tid+off]);
        __syncthreads();
    }
    float mx = red[0]; __syncthreads();
    float lsum = 0.f;
    for (int m = tid; m < NN; m += 256) {
        float e = __expf(row[m] - mx);
        row[m] = e;
        lsum += e;
    }
    red[tid] = lsum; __syncthreads();
    for (int off = 128; off > 0; off >>= 1) {
        if (tid < off) red[tid] += red[tid+off];
        __syncthreads();
    }
    float inv = 1.f / red[0];
    for (int m = tid; m < NN; m += 256) A[n*NN + m] = row[m] * inv;
}

// T2 = 2*A@A - I
__global__ __launch_bounds__(256) void k_cheb(const float* __restrict__ A,
                                              float* __restrict__ T2) {
    int idx = blockIdx.x*256 + threadIdx.x;
    if (idx >= NN*NN) return;
    int n = idx / NN, m = idx % NN;
    float s = 0.f;
    for (int l = 0; l < NN; ++l) s += A[n*NN + l] * A[l*NN + m];
    T2[idx] = 2.f*s - (n == m ? 1.f : 0.f);
}

// Wn[n, kio] = sum_d E[n,d] * pool[d, kio]   (3,686,400 elements)
__global__ __launch_bounds__(256) void k_node_weights(const float* __restrict__ E,
                                                      const float* __restrict__ pool,
                                                      float* __restrict__ Wn) {
    int idx = blockIdx.x*256 + threadIdx.x;   // exact: 14400*256
    int n = idx / KIO, kio = idx % KIO;
    float s = 0.f;
    #pragma unroll
    for (int d = 0; d < 10; ++d) s += E[n*10 + d] * pool[d*KIO + kio];
    Wn[idx] = s;
}

// bN[n,o] = sum_d E[n,d] * bpool[d,o]
__global__ __launch_bounds__(256) void k_node_bias(const float* __restrict__ E,
                                                   const float* __restrict__ bpool,
                                                   float* __restrict__ bN) {
    int idx = blockIdx.x*256 + threadIdx.x;   // exact: 75*256 = 19200
    int n = idx >> 6, o = idx & 63;
    float s = 0.f;
    #pragma unroll
    for (int d = 0; d < 10; ++d) s += E[n*10 + d] * bpool[d*64 + o];
    bN[idx] = s;
}

// Wout fp32 -> fp16 (262144 elems)
__global__ __launch_bounds__(256) void k_cvt_wout(const float* __restrict__ W,
                                                  _Float16* __restrict__ Wh) {
    int idx = blockIdx.x*256 + threadIdx.x;   // exact: 1024*256
    Wh[idx] = (_Float16)W[idx];
}

// h[r,o] = relu( z[r,:]·W_in[o,:] + b_in[o] )  -- 64r x 64o tile per block
__global__ __launch_bounds__(256) void k_in_proj(const float* __restrict__ z,
                                                 const float* __restrict__ Win,
                                                 const float* __restrict__ bin,
                                                 float* __restrict__ h) {
    __shared__ float Wt[64*68];   // Wt[c*68 + o] = Win[o*64 + c]
    __shared__ float zl[64*66];   // zl[rr*66 + c]
    int tx = threadIdx.x, ty = threadIdx.y;   // 16 x 16
    int tid = ty*16 + tx;
    int r0 = blockIdx.y * 64;
    for (int e = tid; e < 4096; e += 256) {
        int o = e >> 6, c = e & 63;
        Wt[c*68 + o] = Win[e];
        zl[o*66 + c] = z[(r0 + o)*64 + c];   // reuse o as rr
    }
    __syncthreads();
    float4 bo = *(const float4*)&bin[tx*4];
    float acc[4][4];
    #pragma unroll
    for (int s = 0; s < 4; ++s) { acc[s][0]=bo.x; acc[s][1]=bo.y; acc[s][2]=bo.z; acc[s][3]=bo.w; }
    const float* zr = &zl[(ty*4)*66];
    for (int c = 0; c < 64; ++c) {
        float4 w = *(const float4*)&Wt[c*68 + tx*4];
        float z0 = zr[c], z1 = zr[66+c], z2 = zr[132+c], z3 = zr[198+c];
        acc[0][0] += z0*w.x; acc[0][1] += z0*w.y; acc[0][2] += z0*w.z; acc[0][3] += z0*w.w;
        acc[1][0] += z1*w.x; acc[1][1] += z1*w.y; acc[1][2] += z1*w.z; acc[1][3] += z1*w.w;
        acc[2][0] += z2*w.x; acc[2][1] += z2*w.y; acc[2][2] += z2*w.z; acc[2][3] += z2*w.w;
        acc[3][0] += z3*w.x; acc[3][1] += z3*w.y; acc[3][2] += z3*w.z; acc[3][3] += z3*w.w;
    }
    #pragma unroll
    for (int s = 0; s < 4; ++s) {
        float4 v = make_float4(fmaxf(acc[s][0],0.f), fmaxf(acc[s][1],0.f),
                               fmaxf(acc[s][2],0.f), fmaxf(acc[s][3],0.f));
        *(float4*)&h[(r0 + ty*4 + s)*64 + tx*4] = v;
    }
}

// Spatial aggregation, restructured for issue efficiency.
// Stacked S = [A (rows 0..299); T2 (rows 300..599)].
// Block = 256 threads = 4 waves; wave owns 5 consecutive S-rows for one b.
// Lane = output channel c. S operands are wave-uniform float4 loads
// (scalar-pipe s_load candidates via readfirstlane-forced uniformity);
// each h[b,m,c] vector load now feeds 5 FMAs instead of 2.
// Grid: (600/20 = 30 row-tiles, 64 b) = 1920 blocks, 7.5 waves/SIMD.
__global__ __launch_bounds__(256) void k_spatial2(const float* __restrict__ A,
                                                  const float* __restrict__ T2,
                                                  const float* __restrict__ h,
                                                  float* __restrict__ xg1,
                                                  float* __restrict__ xg2) {
    int tid = threadIdx.x;
    int c = tid & 63;
    int w = __builtin_amdgcn_readfirstlane(tid >> 6);   // wave id, provably uniform
    int b = blockIdx.y;
    int r0 = blockIdx.x * 20 + w * 5;                   // 0,5,...,595; never straddles 300
    const float* S;
    float* dst;
    if (r0 < NN) {
        S   = A   + (size_t)r0 * NN;
        dst = xg1 + ((size_t)b * NN + r0) * 64 + c;
    } else {
        S   = T2  + (size_t)(r0 - NN) * NN;
        dst = xg2 + ((size_t)b * NN + (r0 - NN)) * 64 + c;
    }
    const float* hb = h + (size_t)b * NN * 64 + c;
    float a0 = 0.f, a1 = 0.f, a2 = 0.f, a3 = 0.f, a4 = 0.f;
    for (int m = 0; m < NN; m += 4) {
        // wave-uniform row chunks (16B aligned: NN*4=1200 and m*4 are mult of 16)
        float4 s0 = *(const float4*)(S + 0*NN + m);
        float4 s1 = *(const float4*)(S + 1*NN + m);
        float4 s2 = *(const float4*)(S + 2*NN + m);
        float4 s3 = *(const float4*)(S + 3*NN + m);
        float4 s4 = *(const float4*)(S + 4*NN + m);
        float h0 = hb[(m+0)*64];
        float h1 = hb[(m+1)*64];
        float h2 = hb[(m+2)*64];
        float h3 = hb[(m+3)*64];
        a0 = fmaf(s0.x,h0,a0); a0 = fmaf(s0.y,h1,a0); a0 = fmaf(s0.z,h2,a0); a0 = fmaf(s0.w,h3,a0);
        a1 = fmaf(s1.x,h0,a1); a1 = fmaf(s1.y,h1,a1); a1 = fmaf(s1.z,h2,a1); a1 = fmaf(s1.w,h3,a1);
        a2 = fmaf(s2.x,h0,a2); a2 = fmaf(s2.y,h1,a2); a2 = fmaf(s2.z,h2,a2); a2 = fmaf(s2.w,h3,a2);
        a3 = fmaf(s3.x,h0,a3); a3 = fmaf(s3.y,h1,a3); a3 = fmaf(s3.z,h2,a3); a3 = fmaf(s3.w,h3,a3);
        a4 = fmaf(s4.x,h0,a4); a4 = fmaf(s4.y,h1,a4); a4 = fmaf(s4.z,h2,a4); a4 = fmaf(s4.w,h3,a4);
    }
    dst[0*64] = a0;
    dst[1*64] = a1;
    dst[2*64] = a2;
    dst[3*64] = a3;
    dst[4*64] = a4;
}

// h2[b,n,o] = bN[n,o] + sum_{ki} xg[b,n,ki] * Wn[n,ki,o]; k=0 slice is h itself.
// Output written as fp16 for the MFMA out-proj. (verbatim from verified version)
__global__ __launch_bounds__(256) void k_node_mm(const float* __restrict__ h,
                                                 const float* __restrict__ xg1,
                                                 const float* __restrict__ xg2,
                                                 const float* __restrict__ Wn,
                                                 const float* __restrict__ bN,
                                                 _Float16* __restrict__ h2h) {
    __shared__ float Wnl[192*64];   // 48 KB
    __shared__ float xgl[8][192];
    int tid = threadIdx.x;
    int o = tid & 63, ty = tid >> 6;
    int n = blockIdx.x, b0 = blockIdx.y*8;
    for (int e = tid; e < 12288; e += 256) Wnl[e] = Wn[(size_t)n*KIO + e];
    for (int e = tid; e < 8*192; e += 256) {
        int bb = e / 192, ki = e % 192;
        int k = ki >> 6, i = ki & 63;
        const float* src = (k == 0) ? h : ((k == 1) ? xg1 : xg2);
        xgl[bb][ki] = src[((b0+bb)*NN + n)*64 + i];
    }
    __syncthreads();
    float bias = bN[n*64 + o];
    for (int bb = ty; bb < 8; bb += 4) {
        float acc = bias;
        for (int ki = 0; ki < 192; ++ki) acc += xgl[bb][ki] * Wnl[ki*64 + o];
        h2h[((b0+bb)*NN + n)*64 + o] = (_Float16)acc;
    }
}

// out[r,j] = tanh( h2[r,:]·Wout[j,:] + bout[j] ), r<19200, j<4096.
// fp16 MFMA 16x16x32, K=64 = 2 k-steps. Fragments loaded straight from
// global, no LDS. Block = 4 waves in 2x2, 128x128 tile; wave = 64x64.
// Output stores are non-temporal: 315 MB write-once stream must not
// displace the L2-resident h2h/Wh tiles that are re-read 32-150x.
__global__ __launch_bounds__(256) void k_out_proj_mfma(const _Float16* __restrict__ h2h,
                                                       const _Float16* __restrict__ Wh,
                                                       const float* __restrict__ bout,
                                                       float* __restrict__ out) {
    int tid  = threadIdx.x;
    int wave = tid >> 6, lane = tid & 63;
    int quad = lane >> 4, lr = lane & 15;
    int m0 = blockIdx.y*128 + (wave >> 1)*64;
    int n0 = blockIdx.x*128 + (wave & 1)*64;
    floatx4 acc[4][4] = {};   // [m-frag][n-frag]
    const _Float16* Aptr = h2h + (size_t)(m0 + lr)*64 + quad*8;
    const _Float16* Bptr = Wh  + (size_t)(n0 + lr)*64 + quad*8;
    #pragma unroll
    for (int ks = 0; ks < 2; ++ks) {
        f16x8 a[4], b[4];
        #pragma unroll
        for (int f = 0; f < 4; ++f) {
            a[f] = *(const f16x8*)(Aptr + (size_t)f*16*64 + ks*32);
            b[f] = *(const f16x8*)(Bptr + (size_t)f*16*64 + ks*32);
        }
        #pragma unroll
        for (int mf = 0; mf < 4; ++mf)
            #pragma unroll
            for (int nf = 0; nf < 4; ++nf)
                acc[mf][nf] = __builtin_amdgcn_mfma_f32_16x16x32_f16(a[mf], b[nf], acc[mf][nf], 0, 0, 0);
    }
    // C/D layout: col = lane&15, row = quad*4 + reg  [m89-verified, dtype-indep]
    #pragma unroll
    for (int nf = 0; nf < 4; ++nf) {
        int col = n0 + nf*16 + lr;
        float bj = bout[col];
        #pragma unroll
        for (int mf = 0; mf < 4; ++mf) {
            int row = m0 + mf*16 + quad*4;
            #pragma unroll
            for (int r = 0; r < 4; ++r) {
                float v = tanh_fast(acc[mf][nf][r] + bj);
                __builtin_nontemporal_store(v, &out[(size_t)(row + r)*JOUT + col]);
            }
        }
    }
}

extern "C" void kernel_launch(void* const* d_in, const int* in_sizes, int n_in,
                              void* d_out, int out_size, void* d_ws, size_t ws_size,
                              hipStream_t stream) {
    const float* z     = (const float*)d_in[0];   // [64,300,64]
    const float* Win   = (const float*)d_in[1];   // [64,64]
    const float* bin   = (const float*)d_in[2];   // [64]
    const float* Wout  = (const float*)d_in[3];   // [4096,64]
    const float* bout  = (const float*)d_in[4];   // [4096]
    const float* E     = (const float*)d_in[5];   // [300,10]
    const float* pool  = (const float*)d_in[6];   // [10,3,64,64]
    const float* bpool = (const float*)d_in[7];   // [10,64]
    float* out = (float*)d_out;                   // [64,300,64,64]

    float* ws  = (float*)d_ws;
    float* A   = ws;                 // 90,000
    float* T2  = A   + 90000;        // 90,000
    float* Wn  = T2  + 90000;        // 3,686,400
    float* bN  = Wn  + 3686400;      // 19,200
    float* h   = bN  + 19200;        // 1,228,800
    float* xg1 = h   + 1228800;      // 1,228,800
    float* xg2 = xg1 + 1228800;      // 1,228,800
    _Float16* h2h  = (_Float16*)(xg2 + 1228800);  // 1,228,800 fp16
    _Float16* Wouth = h2h + 1228800;              // 262,144 fp16  (total ~33.3 MB)

    k_adjacency   <<<NN, 256, 0, stream>>>(E, A);
    k_cheb        <<<(NN*NN + 255)/256, 256, 0, stream>>>(A, T2);
    k_node_weights<<<14400, 256, 0, stream>>>(E, pool, Wn);
    k_node_bias   <<<75, 256, 0, stream>>>(E, bpool, bN);
    k_cvt_wout    <<<1024, 256, 0, stream>>>(Wout, Wouth);
    k_in_proj     <<<dim3(1, RTOT/64), dim3(16,16), 0, stream>>>(z, Win, bin, h);
    k_spatial2    <<<dim3(30, BB), 256, 0, stream>>>(A, T2, h, xg1, xg2);
    k_node_mm     <<<dim3(NN, 8), 256, 0, stream>>>(h, xg1, xg2, Wn, bN, h2h);
    k_out_proj_mfma<<<dim3(JOUT/128, RTOT/128), 256, 0, stream>>>(h2h, Wouth, bout, out);
}

// Round 2
// 454.575 us; speedup vs baseline: 1.0331x; 1.0331x over previous
//
#include <hip/hip_runtime.h>
#include <hip/hip_bf16.h>

// Problem constants (B,N,HC,HH,K,D) = (64,300,64,64,3,10)
#define BB 64
#define NN 300
#define HH 64
#define RTOT (BB*NN)          // 19200 rows
#define KIO  (3*HH*HH)        // 12288: weights_pool inner size per d
#define JOUT (HH*HH)          // 4096 output cols

typedef __attribute__((ext_vector_type(8))) _Float16 f16x8;
typedef __attribute__((ext_vector_type(4))) float floatx4;

__device__ inline float tanh_fast(float x) {
    float e = __expf(2.f * x);
    return 1.f - 2.f * __builtin_amdgcn_rcpf(e + 1.f);
}

// Fused preprocessing: block-role partitioned single dispatch.
//   [0,300)      adjacency: A[n,:] = softmax(relu(E[n]·E[:]))
//   [300,600)    in_proj: h = relu(z@Win^T + bin), 64-row tiles
//   [600,675)    node_bias: bN = E@bpool
//   [675,1699)   cvt_wout: Wout fp32->fp16
//   [1699,16099) node_weights: Wn[n,kio] = sum_d E[n,d] pool[d,kio]
// Critical-path roles (adjacency, in_proj) dispatch first.
// Shared buffer = max(role needs) = in_proj's 8576 floats (33.5 KB) -> 4 blk/CU.
__global__ __launch_bounds__(256) void k_pre(const float* __restrict__ E,
                                             const float* __restrict__ z,
                                             const float* __restrict__ Win,
                                             const float* __restrict__ bin,
                                             const float* __restrict__ Wout,
                                             const float* __restrict__ pool,
                                             const float* __restrict__ bpool,
                                             float* __restrict__ A,
                                             float* __restrict__ h,
                                             float* __restrict__ Wn,
                                             float* __restrict__ bN,
                                             _Float16* __restrict__ Wh) {
    __shared__ float smem[8576];
    int bid = blockIdx.x, tid = threadIdx.x;

    if (bid < 300) {
        // ---- adjacency ----
        float* sE  = smem;          // 16
        float* row = smem + 16;     // 300
        float* red = smem + 320;    // 256
        int n = bid;
        if (tid < 10) sE[tid] = E[n*10 + tid];
        __syncthreads();
        float lmax = -1e30f;
        for (int m = tid; m < NN; m += 256) {
            float s = 0.f;
            #pragma unroll
            for (int d = 0; d < 10; ++d) s += sE[d] * E[m*10 + d];
            s = fmaxf(s, 0.f);
            row[m] = s;
            lmax = fmaxf(lmax, s);
        }
        red[tid] = lmax; __syncthreads();
        for (int off = 128; off > 0; off >>= 1) {
            if (tid < off) red[tid] = fmaxf(red[tid], red[tid+off]);
            __syncthreads();
        }
        float mx = red[0]; __syncthreads();
        float lsum = 0.f;
        for (int m = tid; m < NN; m += 256) {
            float e = __expf(row[m] - mx);
            row[m] = e;
            lsum += e;
        }
        red[tid] = lsum; __syncthreads();
        for (int off = 128; off > 0; off >>= 1) {
            if (tid < off) red[tid] += red[tid+off];
            __syncthreads();
        }
        float inv = 1.f / red[0];
        for (int m = tid; m < NN; m += 256) A[n*NN + m] = row[m] * inv;
    } else if (bid < 600) {
        // ---- in_proj: 64r x 64o tile ----
        float* Wt = smem;           // 64*68
        float* zl = smem + 4352;    // 64*66
        int tx = tid & 15, ty = tid >> 4;
        int r0 = (bid - 300) * 64;
        for (int e = tid; e < 4096; e += 256) {
            int o = e >> 6, c = e & 63;
            Wt[c*68 + o] = Win[e];
            zl[o*66 + c] = z[(size_t)(r0 + o)*64 + c];
        }
        __syncthreads();
        float4 bo = *(const float4*)&bin[tx*4];
        float acc[4][4];
        #pragma unroll
        for (int s = 0; s < 4; ++s) { acc[s][0]=bo.x; acc[s][1]=bo.y; acc[s][2]=bo.z; acc[s][3]=bo.w; }
        const float* zr = &zl[(ty*4)*66];
        for (int c = 0; c < 64; ++c) {
            float4 w = *(const float4*)&Wt[c*68 + tx*4];
            float z0 = zr[c], z1 = zr[66+c], z2 = zr[132+c], z3 = zr[198+c];
            acc[0][0] += z0*w.x; acc[0][1] += z0*w.y; acc[0][2] += z0*w.z; acc[0][3] += z0*w.w;
            acc[1][0] += z1*w.x; acc[1][1] += z1*w.y; acc[1][2] += z1*w.z; acc[1][3] += z1*w.w;
            acc[2][0] += z2*w.x; acc[2][1] += z2*w.y; acc[2][2] += z2*w.z; acc[2][3] += z2*w.w;
            acc[3][0] += z3*w.x; acc[3][1] += z3*w.y; acc[3][2] += z3*w.z; acc[3][3] += z3*w.w;
        }
        #pragma unroll
        for (int s = 0; s < 4; ++s) {
            float4 v = make_float4(fmaxf(acc[s][0],0.f), fmaxf(acc[s][1],0.f),
                                   fmaxf(acc[s][2],0.f), fmaxf(acc[s][3],0.f));
            *(float4*)&h[(size_t)(r0 + ty*4 + s)*64 + tx*4] = v;
        }
    } else if (bid < 675) {
        // ---- node_bias ----
        int idx = (bid - 600)*256 + tid;   // < 19200
        int n = idx >> 6, o = idx & 63;
        float s = 0.f;
        #pragma unroll
        for (int d = 0; d < 10; ++d) s += E[n*10 + d] * bpool[d*64 + o];
        bN[idx] = s;
    } else if (bid < 1699) {
        // ---- cvt_wout ----
        int idx = (bid - 675)*256 + tid;   // < 262144
        Wh[idx] = (_Float16)Wout[idx];
    } else {
        // ---- node_weights ----
        int idx = (bid - 1699)*256 + tid;  // < 3,686,400
        int n = idx / KIO, kio = idx % KIO;
        float s = 0.f;
        #pragma unroll
        for (int d = 0; d < 10; ++d) s += E[n*10 + d] * pool[d*KIO + kio];
        Wn[idx] = s;
    }
}

// xg1[b,r,c] = sum_m A[r,m] h[b,m,c].
// Wave owns 5 rows of A for one b; lane = channel c. A chunks are
// wave-uniform float4 loads; each h load feeds 5 FMAs.
// Grid (15, 64) = 960 blocks.
__global__ __launch_bounds__(256) void k_spatialA(const float* __restrict__ A,
                                                  const float* __restrict__ h,
                                                  float* __restrict__ xg1) {
    int tid = threadIdx.x;
    int c = tid & 63;
    int w = __builtin_amdgcn_readfirstlane(tid >> 6);
    int b = blockIdx.y;
    int r0 = blockIdx.x * 20 + w * 5;                  // 0..295
    const float* S = A + (size_t)r0 * NN;
    const float* hb = h + (size_t)b * NN * 64 + c;
    float a0 = 0.f, a1 = 0.f, a2 = 0.f, a3 = 0.f, a4 = 0.f;
    for (int m = 0; m < NN; m += 4) {
        float4 s0 = *(const float4*)(S + 0*NN + m);
        float4 s1 = *(const float4*)(S + 1*NN + m);
        float4 s2 = *(const float4*)(S + 2*NN + m);
        float4 s3 = *(const float4*)(S + 3*NN + m);
        float4 s4 = *(const float4*)(S + 4*NN + m);
        float h0 = hb[(m+0)*64];
        float h1 = hb[(m+1)*64];
        float h2 = hb[(m+2)*64];
        float h3 = hb[(m+3)*64];
        a0 = fmaf(s0.x,h0,a0); a0 = fmaf(s0.y,h1,a0); a0 = fmaf(s0.z,h2,a0); a0 = fmaf(s0.w,h3,a0);
        a1 = fmaf(s1.x,h0,a1); a1 = fmaf(s1.y,h1,a1); a1 = fmaf(s1.z,h2,a1); a1 = fmaf(s1.w,h3,a1);
        a2 = fmaf(s2.x,h0,a2); a2 = fmaf(s2.y,h1,a2); a2 = fmaf(s2.z,h2,a2); a2 = fmaf(s2.w,h3,a2);
        a3 = fmaf(s3.x,h0,a3); a3 = fmaf(s3.y,h1,a3); a3 = fmaf(s3.z,h2,a3); a3 = fmaf(s3.w,h3,a3);
        a4 = fmaf(s4.x,h0,a4); a4 = fmaf(s4.y,h1,a4); a4 = fmaf(s4.z,h2,a4); a4 = fmaf(s4.w,h3,a4);
    }
    float* dst = xg1 + ((size_t)b * NN + r0) * 64 + c;
    dst[0*64] = a0; dst[1*64] = a1; dst[2*64] = a2; dst[3*64] = a3; dst[4*64] = a4;
}

// Chebyshev on features instead of support matrix:
//   xg2 = T2@h = (2A^2 - I)h = 2*A@xg1 - h      (k_cheb eliminated)
__global__ __launch_bounds__(256) void k_spatialB(const float* __restrict__ A,
                                                  const float* __restrict__ xg1,
                                                  const float* __restrict__ h,
                                                  float* __restrict__ xg2) {
    int tid = threadIdx.x;
    int c = tid & 63;
    int w = __builtin_amdgcn_readfirstlane(tid >> 6);
    int b = blockIdx.y;
    int r0 = blockIdx.x * 20 + w * 5;
    const float* S = A + (size_t)r0 * NN;
    const float* xb = xg1 + (size_t)b * NN * 64 + c;
    float a0 = 0.f, a1 = 0.f, a2 = 0.f, a3 = 0.f, a4 = 0.f;
    for (int m = 0; m < NN; m += 4) {
        float4 s0 = *(const float4*)(S + 0*NN + m);
        float4 s1 = *(const float4*)(S + 1*NN + m);
        float4 s2 = *(const float4*)(S + 2*NN + m);
        float4 s3 = *(const float4*)(S + 3*NN + m);
        float4 s4 = *(const float4*)(S + 4*NN + m);
        float x0 = xb[(m+0)*64];
        float x1 = xb[(m+1)*64];
        float x2 = xb[(m+2)*64];
        float x3 = xb[(m+3)*64];
        a0 = fmaf(s0.x,x0,a0); a0 = fmaf(s0.y,x1,a0); a0 = fmaf(s0.z,x2,a0); a0 = fmaf(s0.w,x3,a0);
        a1 = fmaf(s1.x,x0,a1); a1 = fmaf(s1.y,x1,a1); a1 = fmaf(s1.z,x2,a1); a1 = fmaf(s1.w,x3,a1);
        a2 = fmaf(s2.x,x0,a2); a2 = fmaf(s2.y,x1,a2); a2 = fmaf(s2.z,x2,a2); a2 = fmaf(s2.w,x3,a2);
        a3 = fmaf(s3.x,x0,a3); a3 = fmaf(s3.y,x1,a3); a3 = fmaf(s3.z,x2,a3); a3 = fmaf(s3.w,x3,a3);
        a4 = fmaf(s4.x,x0,a4); a4 = fmaf(s4.y,x1,a4); a4 = fmaf(s4.z,x2,a4); a4 = fmaf(s4.w,x3,a4);
    }
    const float* hb = h   + ((size_t)b * NN + r0) * 64 + c;
    float*       dst = xg2 + ((size_t)b * NN + r0) * 64 + c;
    dst[0*64] = 2.f*a0 - hb[0*64];
    dst[1*64] = 2.f*a1 - hb[1*64];
    dst[2*64] = 2.f*a2 - hb[2*64];
    dst[3*64] = 2.f*a3 - hb[3*64];
    dst[4*64] = 2.f*a4 - hb[4*64];
}

// h2[b,n,o] = bN[n,o] + sum_{ki} xg[b,n,ki] * Wn[n,ki,o]; k=0 slice is h itself.
__global__ __launch_bounds__(256) void k_node_mm(const float* __restrict__ h,
                                                 const float* __restrict__ xg1,
                                                 const float* __restrict__ xg2,
                                                 const float* __restrict__ Wn,
                                                 const float* __restrict__ bN,
                                                 _Float16* __restrict__ h2h) {
    __shared__ float Wnl[192*64];   // 48 KB
    __shared__ float xgl[8][192];
    int tid = threadIdx.x;
    int o = tid & 63, ty = tid >> 6;
    int n = blockIdx.x, b0 = blockIdx.y*8;
    for (int e = tid; e < 12288; e += 256) Wnl[e] = Wn[(size_t)n*KIO + e];
    for (int e = tid; e < 8*192; e += 256) {
        int bb = e / 192, ki = e % 192;
        int k = ki >> 6, i = ki & 63;
        const float* src = (k == 0) ? h : ((k == 1) ? xg1 : xg2);
        xgl[bb][ki] = src[((b0+bb)*NN + n)*64 + i];
    }
    __syncthreads();
    float bias = bN[n*64 + o];
    for (int bb = ty; bb < 8; bb += 4) {
        float acc = bias;
        for (int ki = 0; ki < 192; ++ki) acc += xgl[bb][ki] * Wnl[ki*64 + o];
        h2h[((b0+bb)*NN + n)*64 + o] = (_Float16)acc;
    }
}

// out[r,j] = tanh( h2[r,:]·Wout[j,:] + bout[j] ), fp16 MFMA 16x16x32.
// Non-temporal stores: 315 MB write-once stream must not displace
// the L2-resident h2h/Wh tiles.
__global__ __launch_bounds__(256) void k_out_proj_mfma(const _Float16* __restrict__ h2h,
                                                       const _Float16* __restrict__ Wh,
                                                       const float* __restrict__ bout,
                                                       float* __restrict__ out) {
    int tid  = threadIdx.x;
    int wave = tid >> 6, lane = tid & 63;
    int quad = lane >> 4, lr = lane & 15;
    int m0 = blockIdx.y*128 + (wave >> 1)*64;
    int n0 = blockIdx.x*128 + (wave & 1)*64;
    floatx4 acc[4][4] = {};   // [m-frag][n-frag]
    const _Float16* Aptr = h2h + (size_t)(m0 + lr)*64 + quad*8;
    const _Float16* Bptr = Wh  + (size_t)(n0 + lr)*64 + quad*8;
    #pragma unroll
    for (int ks = 0; ks < 2; ++ks) {
        f16x8 a[4], b[4];
        #pragma unroll
        for (int f = 0; f < 4; ++f) {
            a[f] = *(const f16x8*)(Aptr + (size_t)f*16*64 + ks*32);
            b[f] = *(const f16x8*)(Bptr + (size_t)f*16*64 + ks*32);
        }
        #pragma unroll
        for (int mf = 0; mf < 4; ++mf)
            #pragma unroll
            for (int nf = 0; nf < 4; ++nf)
                acc[mf][nf] = __builtin_amdgcn_mfma_f32_16x16x32_f16(a[mf], b[nf], acc[mf][nf], 0, 0, 0);
    }
    // C/D layout: col = lane&15, row = quad*4 + reg  [m89-verified, dtype-indep]
    #pragma unroll
    for (int nf = 0; nf < 4; ++nf) {
        int col = n0 + nf*16 + lr;
        float bj = bout[col];
        #pragma unroll
        for (int mf = 0; mf < 4; ++mf) {
            int row = m0 + mf*16 + quad*4;
            #pragma unroll
            for (int r = 0; r < 4; ++r) {
                float v = tanh_fast(acc[mf][nf][r] + bj);
                __builtin_nontemporal_store(v, &out[(size_t)(row + r)*JOUT + col]);
            }
        }
    }
}

extern "C" void kernel_launch(void* const* d_in, const int* in_sizes, int n_in,
                              void* d_out, int out_size, void* d_ws, size_t ws_size,
                              hipStream_t stream) {
    const float* z     = (const float*)d_in[0];   // [64,300,64]
    const float* Win   = (const float*)d_in[1];   // [64,64]
    const float* bin   = (const float*)d_in[2];   // [64]
    const float* Wout  = (const float*)d_in[3];   // [4096,64]
    const float* bout  = (const float*)d_in[4];   // [4096]
    const float* E     = (const float*)d_in[5];   // [300,10]
    const float* pool  = (const float*)d_in[6];   // [10,3,64,64]
    const float* bpool = (const float*)d_in[7];   // [10,64]
    float* out = (float*)d_out;                   // [64,300,64,64]

    float* ws  = (float*)d_ws;
    float* A   = ws;                 // 90,000
    float* Wn  = A   + 90000;        // 3,686,400
    float* bN  = Wn  + 3686400;      // 19,200
    float* h   = bN  + 19200;        // 1,228,800
    float* xg1 = h   + 1228800;      // 1,228,800
    float* xg2 = xg1 + 1228800;      // 1,228,800
    _Float16* h2h   = (_Float16*)(xg2 + 1228800); // 1,228,800 fp16
    _Float16* Wouth = h2h + 1228800;              // 262,144 fp16 (total ~33 MB)

    k_pre      <<<16099, 256, 0, stream>>>(E, z, Win, bin, Wout, pool, bpool,
                                           A, h, Wn, bN, Wouth);
    k_spatialA <<<dim3(15, BB), 256, 0, stream>>>(A, h, xg1);
    k_spatialB <<<dim3(15, BB), 256, 0, stream>>>(A, xg1, h, xg2);
    k_node_mm  <<<dim3(NN, 8), 256, 0, stream>>>(h, xg1, xg2, Wn, bN, h2h);
    k_out_proj_mfma<<<dim3(JOUT/128, RTOT/128), 256, 0, stream>>>(h2h, Wouth, bout, out);
}